// Round 5
// baseline (48754.092 us; speedup 1.0000x reference)
//
#include <hip/hip_runtime.h>
#include <math.h>

#define IN_SIZE 96
#define HID 128
#define H3 384
#define LIN_IN 32

// ---------------------------------------------------------------------------
// Kernel A (parallel): igates[t][j] = dot(input_GRU[t,:], w_ih[j,:]) + b_ih[j]
// ---------------------------------------------------------------------------
__global__ __launch_bounds__(384, 2)
void igates_kernel(const float* __restrict__ x, const float* __restrict__ w_ih,
                   const float* __restrict__ b_ih, float* __restrict__ ig, int T)
{
    const int TT = 16;
    int t0 = blockIdx.x * TT;
    int j = threadIdx.x; // 0..383
    __shared__ __align__(16) float xs[TT * IN_SIZE]; // 6 KB
    for (int idx = j; idx < TT * IN_SIZE; idx += H3)
        xs[idx] = x[(size_t)t0 * IN_SIZE + idx];
    __syncthreads();

    float acc[TT];
    float b = b_ih[j];
#pragma unroll
    for (int tt = 0; tt < TT; tt++) acc[tt] = b;

    const float4* w4 = (const float4*)(w_ih + (size_t)j * IN_SIZE);
#pragma unroll
    for (int k = 0; k < IN_SIZE / 4; k++) {
        float4 wv = w4[k];
#pragma unroll
        for (int tt = 0; tt < TT; tt++) {
            const float4* xv4 = (const float4*)(xs + tt * IN_SIZE);
            float4 xv = xv4[k];
            acc[tt] = fmaf(wv.x, xv.x, acc[tt]);
            acc[tt] = fmaf(wv.y, xv.y, acc[tt]);
            acc[tt] = fmaf(wv.z, xv.z, acc[tt]);
            acc[tt] = fmaf(wv.w, xv.w, acc[tt]);
        }
    }
#pragma unroll
    for (int tt = 0; tt < TT; tt++)
        ig[(size_t)(t0 + tt) * H3 + j] = acc[tt];
}

// ---------------------------------------------------------------------------
// Kernel B (sequential scan): one workgroup, 384 threads = 6 waves.
// thread tid -> rg = tid>>2 (4-row group), kseg = tid&3 (32-wide k slice).
// 4x32 w_hh weights per thread in registers (literal indices only -- R2's
// dynamic index spilled everything; R3 fixed it via padded-h layout).
//
// R4 changes (vs R3's 1530 cyc/step, ~60% stall):
//  - RAW BARRIERS: "s_waitcnt lgkmcnt(0); s_barrier" inline asm instead of
//    __syncthreads(). __syncthreads emits s_waitcnt vmcnt(0) which drained
//    the igates prefetch stream at EVERY barrier (~500-900 cyc HBM stall per
//    step). Raw barrier keeps global loads in flight; compiler auto-inserts
//    vmcnt(N) at the register consume point instead.
//  - PREFETCH DEPTH 2: consume at step s what was issued at s-2 (~2 steps of
//    latency budget, covers HBM-miss ~900 cyc).
//  - SHFL K-COMBINE: kseg partials live in adjacent lanes (tid=4rg+kseg);
//    butterfly shfl_xor 1,2 (quad-perm DPP, no LDS) replaces the
//    hgp-write + 12-LDS-read reduction. Only kseg==0 lanes write the final
//    row sums (natural row order), gate threads read 3 floats.
// ---------------------------------------------------------------------------
__device__ __forceinline__ void fma4(float4& acc, const float4& wv, const float4& hv)
{
    acc.x = fmaf(wv.x, hv.x, acc.x);
    acc.y = fmaf(wv.y, hv.y, acc.y);
    acc.z = fmaf(wv.z, hv.z, acc.z);
    acc.w = fmaf(wv.w, hv.w, acc.w);
}

__device__ __forceinline__ void fast_barrier()
{
    // LDS visibility only; leave vmcnt outstanding across the barrier.
    asm volatile("s_waitcnt lgkmcnt(0)\n\ts_barrier" ::: "memory");
}

#define HPAD 36  // 32 floats per k-segment + 4 pad (bank-quad disjoint reads)

__global__ __launch_bounds__(384, 1)
void scan_kernel(const float* __restrict__ ig, const float* __restrict__ h0,
                 const float* __restrict__ w_hh, const float* __restrict__ b_n,
                 float* __restrict__ hlin, int T)
{
    __shared__ __align__(16) float hs[4 * HPAD];   // padded h
    __shared__ __align__(16) float4 hg4[96];       // row sums, natural order

    const int tid = threadIdx.x;     // 0..383
    const int rg = tid >> 2;         // 0..95
    const int kseg = tid & 3;        // 0..3

    // this thread's 4x32 weight tile -> registers (literal indices only)
    float4 w0[8], w1[8], w2[8], w3[8];
    {
        const float* base = w_hh + (size_t)(4 * rg) * HID + kseg * 32;
#pragma unroll
        for (int k = 0; k < 8; k++) {
            w0[k] = ((const float4*)(base + 0 * HID))[k];
            w1[k] = ((const float4*)(base + 1 * HID))[k];
            w2[k] = ((const float4*)(base + 2 * HID))[k];
            w3[k] = ((const float4*)(base + 3 * HID))[k];
        }
    }
    if (tid < HID) hs[(tid >> 5) * HPAD + (tid & 31)] = h0[tid];

    // igates pipeline: c* = step s, n* = step s+1, loaded m* = step s+2
    float bn = 0.f;
    float c0 = 0.f, c1 = 0.f, c2 = 0.f, n0 = 0.f, n1 = 0.f, n2 = 0.f;
    if (tid < HID) {
        bn = b_n[tid];
        c0 = ig[tid];
        c1 = ig[HID + tid];
        c2 = ig[2 * HID + tid];
        const float* p = ig + H3;
        n0 = p[tid];
        n1 = p[HID + tid];
        n2 = p[2 * HID + tid];
    }
    __syncthreads();

    const float4* hp = (const float4*)(hs + kseg * HPAD);
    const int hidx = (tid >> 5) * HPAD + (tid & 31);
    const float* hgf = (const float*)hg4;

    for (int step = 0; step < T; ++step) {
        // prefetch step+2's gate inputs (consumed two steps from now)
        float m0 = 0.f, m1 = 0.f, m2 = 0.f;
        if (step + 2 < T && tid < HID) {
            const float* p = ig + (size_t)(step + 2) * H3;
            m0 = p[tid];
            m1 = p[HID + tid];
            m2 = p[2 * HID + tid];
        }

        // matvec: 4 rows x 32 k per thread, conflict-free padded h reads
        float4 a0 = {0.f, 0.f, 0.f, 0.f}, a1 = a0, a2 = a0, a3 = a0;
#pragma unroll
        for (int kk = 0; kk < 8; kk++) {
            float4 hv = hp[kk];
            fma4(a0, w0[kk], hv);
            fma4(a1, w1[kk], hv);
            fma4(a2, w2[kk], hv);
            fma4(a3, w3[kk], hv);
        }
        float4 s;
        s.x = (a0.x + a0.y) + (a0.z + a0.w);
        s.y = (a1.x + a1.y) + (a1.z + a1.w);
        s.z = (a2.x + a2.y) + (a2.z + a2.w);
        s.w = (a3.x + a3.y) + (a3.z + a3.w);
        // combine the 4 kseg partials (adjacent lanes) via quad-perm DPP
        s.x += __shfl_xor(s.x, 1); s.y += __shfl_xor(s.y, 1);
        s.z += __shfl_xor(s.z, 1); s.w += __shfl_xor(s.w, 1);
        s.x += __shfl_xor(s.x, 2); s.y += __shfl_xor(s.y, 2);
        s.z += __shfl_xor(s.z, 2); s.w += __shfl_xor(s.w, 2);
        if (kseg == 0) hg4[rg] = s;   // rows 4rg..4rg+3 in natural order
        fast_barrier();

        if (tid < HID) {
            float hr = hgf[tid];
            float hz = hgf[HID + tid];
            float hn = hgf[2 * HID + tid];
            float hprev = hs[hidx];
            float er = __expf(-(c0 + hr));
            float r = __builtin_amdgcn_rcpf(1.f + er);
            float ez = __expf(-(c1 + hz));
            float z = __builtin_amdgcn_rcpf(1.f + ez);
            float xn = c2 + r * (hn + bn);
            float e2 = __expf(-2.f * fabsf(xn));
            float th = (1.f - e2) * __builtin_amdgcn_rcpf(1.f + e2);
            float nn = copysignf(th, xn);
            float hnew = nn + z * (hprev - nn);
            hs[hidx] = hnew;
            if (tid < LIN_IN)
                hlin[(size_t)step * LIN_IN + tid] = hnew; // readout deferred
        }
        c0 = n0; c1 = n1; c2 = n2;
        n0 = m0; n1 = m1; n2 = m2;
        fast_barrier();
    }
}

// ---------------------------------------------------------------------------
// Kernel C (parallel): out[t] = dot(hlin[t,:], xlin[t,:]) + lbias
// ---------------------------------------------------------------------------
__global__ __launch_bounds__(256)
void readout_kernel(const float* __restrict__ hlin, const float* __restrict__ xlin,
                    const float* __restrict__ lbias, float* __restrict__ out, int T)
{
    int gid = blockIdx.x * 256 + threadIdx.x;
    int t = gid >> 3;
    int seg = gid & 7;
    if (t < T) {
        float4 hv = ((const float4*)hlin)[(size_t)t * 8 + seg];
        float4 xv = ((const float4*)xlin)[(size_t)t * 8 + seg];
        float p = hv.x * xv.x + hv.y * xv.y + hv.z * xv.z + hv.w * xv.w;
        p += __shfl_xor(p, 1);
        p += __shfl_xor(p, 2);
        p += __shfl_xor(p, 4);
        if (seg == 0) out[t] = p + lbias[0];
    }
}

extern "C" void kernel_launch(void* const* d_in, const int* in_sizes, int n_in,
                              void* d_out, int out_size, void* d_ws, size_t ws_size,
                              hipStream_t stream) {
    const float* x_gru = (const float*)d_in[0];  // (T, 96)
    const float* x_lin = (const float*)d_in[1];  // (T, 32)
    const float* h0    = (const float*)d_in[2];  // (128,)
    const float* w_ih  = (const float*)d_in[3];  // (384, 96)
    const float* w_hh  = (const float*)d_in[4];  // (384, 128)
    const float* b_ih  = (const float*)d_in[5];  // (384,)
    const float* b_n   = (const float*)d_in[6];  // (128,)
    const float* lbias = (const float*)d_in[7];  // (1,)
    float* out = (float*)d_out;                  // (T, 1)

    int T = in_sizes[0] / IN_SIZE;
    float* igates = (float*)d_ws;                    // T*384 floats = 96 MiB
    float* hlin   = (float*)d_ws + (size_t)T * H3;   // T*32 floats  =  8 MiB

    igates_kernel<<<T / 16, 384, 0, stream>>>(x_gru, w_ih, b_ih, igates, T);
    scan_kernel<<<1, 384, 0, stream>>>(igates, h0, w_hh, b_n, hlin, T);
    readout_kernel<<<(T * 8 + 255) / 256, 256, 0, stream>>>(hlin, x_lin, lbias, out, T);
}

// Round 6
// 34887.592 us; speedup vs baseline: 1.3975x; 1.3975x over previous
//
#include <hip/hip_runtime.h>
#include <math.h>

#define IN_SIZE 96
#define HID 128
#define H3 384
#define LIN_IN 32

// ---------------------------------------------------------------------------
// Kernel A (parallel): igates[t][j] = dot(input_GRU[t,:], w_ih[j,:]) + b_ih[j]
// ---------------------------------------------------------------------------
__global__ __launch_bounds__(384, 2)
void igates_kernel(const float* __restrict__ x, const float* __restrict__ w_ih,
                   const float* __restrict__ b_ih, float* __restrict__ ig, int T)
{
    const int TT = 16;
    int t0 = blockIdx.x * TT;
    int j = threadIdx.x; // 0..383
    __shared__ __align__(16) float xs[TT * IN_SIZE]; // 6 KB
    for (int idx = j; idx < TT * IN_SIZE; idx += H3)
        xs[idx] = x[(size_t)t0 * IN_SIZE + idx];
    __syncthreads();

    float acc[TT];
    float b = b_ih[j];
#pragma unroll
    for (int tt = 0; tt < TT; tt++) acc[tt] = b;

    const float4* w4 = (const float4*)(w_ih + (size_t)j * IN_SIZE);
#pragma unroll
    for (int k = 0; k < IN_SIZE / 4; k++) {
        float4 wv = w4[k];
#pragma unroll
        for (int tt = 0; tt < TT; tt++) {
            const float4* xv4 = (const float4*)(xs + tt * IN_SIZE);
            float4 xv = xv4[k];
            acc[tt] = fmaf(wv.x, xv.x, acc[tt]);
            acc[tt] = fmaf(wv.y, xv.y, acc[tt]);
            acc[tt] = fmaf(wv.z, xv.z, acc[tt]);
            acc[tt] = fmaf(wv.w, xv.w, acc[tt]);
        }
    }
#pragma unroll
    for (int tt = 0; tt < TT; tt++)
        ig[(size_t)(t0 + tt) * H3 + j] = acc[tt];
}

// ---------------------------------------------------------------------------
// Kernel B (sequential scan): one workgroup, 512 threads = 8 waves (2/SIMD,
// balanced -- 6 waves left 2 SIMDs with double FMA issue load).
// thread tid -> j = tid>>2 (0..127), kseg = tid&3 (32-wide k slice).
// Thread owns rows {j, j+128, j+256} -- i.e. ALL THREE GATES of hidden unit
// j. After the quad k-combine, the kseg==0 lane has hr,hz,hn for its j and
// computes hnew[j] directly: ONE barrier per step (R3/R4 had two + an LDS
// roundtrip for the partial sums).
// k-combine is quad_perm DPP (pure VALU) -- R4's __shfl_xor lowered to
// ds_bpermute (LDS pipe, ~120cyc latency x 2 dependent stages = the R4
// regression).
// Weights: 3 rows x 32 k per thread in registers, literal indices only
// (R2's dynamic index spilled everything to scratch).
// h layout padded: hs[kseg*36 + off] -> the 4 concurrent kseg addresses hit
// disjoint bank quads; 16-way same-address broadcast within each is free.
// ---------------------------------------------------------------------------
__device__ __forceinline__ void fma4(float4& acc, const float4& wv, const float4& hv)
{
    acc.x = fmaf(wv.x, hv.x, acc.x);
    acc.y = fmaf(wv.y, hv.y, acc.y);
    acc.z = fmaf(wv.z, hv.z, acc.z);
    acc.w = fmaf(wv.w, hv.w, acc.w);
}

__device__ __forceinline__ float quad_sum(float x)
{
    // sum over the 4 lanes of a quad: two quad_perm DPP add stages (VALU only)
    float t;
    t = __int_as_float(__builtin_amdgcn_mov_dpp(__float_as_int(x), 0xB1, 0xF, 0xF, true)); // [1,0,3,2]
    x += t;
    t = __int_as_float(__builtin_amdgcn_mov_dpp(__float_as_int(x), 0x4E, 0xF, 0xF, true)); // [2,3,0,1]
    x += t;
    return x;
}

__device__ __forceinline__ void fast_barrier()
{
    // LDS visibility only; leave global loads in flight across the barrier.
    asm volatile("s_waitcnt lgkmcnt(0)\n\ts_barrier" ::: "memory");
}

#define HPAD 36  // 32 floats per k-segment + 4 pad

__global__ __launch_bounds__(512, 2)
void scan_kernel(const float* __restrict__ ig, const float* __restrict__ h0,
                 const float* __restrict__ w_hh, const float* __restrict__ b_n,
                 float* __restrict__ hlin, int T)
{
    __shared__ __align__(16) float hs[4 * HPAD];   // padded h (576 B)

    const int tid = threadIdx.x;     // 0..511
    const int j = tid >> 2;          // 0..127 (hidden unit)
    const int kseg = tid & 3;        // 0..3   (32-wide k slice)
    const bool gate_lane = (kseg == 0);

    // weights for rows j, j+128, j+256 (k slice kseg*32..+32) -> registers
    float4 w0[8], w1[8], w2[8];
    {
        const float* b0 = w_hh + (size_t)j * HID + kseg * 32;
        const float* b1 = w_hh + (size_t)(j + HID) * HID + kseg * 32;
        const float* b2 = w_hh + (size_t)(j + 2 * HID) * HID + kseg * 32;
#pragma unroll
        for (int k = 0; k < 8; k++) {
            w0[k] = ((const float4*)b0)[k];
            w1[k] = ((const float4*)b1)[k];
            w2[k] = ((const float4*)b2)[k];
        }
    }
    if (tid < HID) hs[(tid >> 5) * HPAD + (tid & 31)] = h0[tid];

    // per-step gate inputs (only gate lanes hold real values)
    float bn = 0.f, c0 = 0.f, c1 = 0.f, c2 = 0.f;
    if (gate_lane) {
        bn = b_n[j];
        c0 = ig[j];
        c1 = ig[HID + j];
        c2 = ig[2 * HID + j];
    }
    __syncthreads();

    const float4* hp = (const float4*)(hs + kseg * HPAD);
    const int hwidx = (j >> 5) * HPAD + (j & 31);  // gate lane's h slot

    for (int step = 0; step < T; ++step) {
        // prefetch next step's gate inputs (consumed after the matvec)
        float n0 = 0.f, n1 = 0.f, n2 = 0.f;
        if (gate_lane && step + 1 < T) {
            const float* p = ig + (size_t)(step + 1) * H3;
            n0 = p[j];
            n1 = p[HID + j];
            n2 = p[2 * HID + j];
        }

        // matvec: 3 gate rows x 32 k per thread, conflict-free padded h reads
        float4 a0 = {0.f, 0.f, 0.f, 0.f}, a1 = a0, a2 = a0;
#pragma unroll
        for (int kk = 0; kk < 8; kk++) {
            float4 hv = hp[kk];
            fma4(a0, w0[kk], hv);
            fma4(a1, w1[kk], hv);
            fma4(a2, w2[kk], hv);
        }
        float s0 = (a0.x + a0.y) + (a0.z + a0.w);
        float s1 = (a1.x + a1.y) + (a1.z + a1.w);
        float s2 = (a2.x + a2.y) + (a2.z + a2.w);
        // combine the 4 kseg partials within each quad (pure-VALU DPP)
        s0 = quad_sum(s0);
        s1 = quad_sum(s1);
        s2 = quad_sum(s2);

        if (gate_lane) {
            float hprev = hs[hwidx];
            float er = __expf(-(c0 + s0));
            float r = __builtin_amdgcn_rcpf(1.f + er);
            float ez = __expf(-(c1 + s1));
            float z = __builtin_amdgcn_rcpf(1.f + ez);
            float xn = c2 + r * (s2 + bn);
            float e2 = __expf(-2.f * fabsf(xn));
            float th = (1.f - e2) * __builtin_amdgcn_rcpf(1.f + e2);
            float nn = copysignf(th, xn);
            float hnew = nn + z * (hprev - nn);
            hs[hwidx] = hnew;
            if (j < LIN_IN)
                hlin[(size_t)step * LIN_IN + j] = hnew; // readout deferred
        }
        c0 = n0; c1 = n1; c2 = n2;
        fast_barrier();  // hs visible -> next matvec
    }
}

// ---------------------------------------------------------------------------
// Kernel C (parallel): out[t] = dot(hlin[t,:], xlin[t,:]) + lbias
// ---------------------------------------------------------------------------
__global__ __launch_bounds__(256)
void readout_kernel(const float* __restrict__ hlin, const float* __restrict__ xlin,
                    const float* __restrict__ lbias, float* __restrict__ out, int T)
{
    int gid = blockIdx.x * 256 + threadIdx.x;
    int t = gid >> 3;
    int seg = gid & 7;
    if (t < T) {
        float4 hv = ((const float4*)hlin)[(size_t)t * 8 + seg];
        float4 xv = ((const float4*)xlin)[(size_t)t * 8 + seg];
        float p = hv.x * xv.x + hv.y * xv.y + hv.z * xv.z + hv.w * xv.w;
        p += __shfl_xor(p, 1);
        p += __shfl_xor(p, 2);
        p += __shfl_xor(p, 4);
        if (seg == 0) out[t] = p + lbias[0];
    }
}

extern "C" void kernel_launch(void* const* d_in, const int* in_sizes, int n_in,
                              void* d_out, int out_size, void* d_ws, size_t ws_size,
                              hipStream_t stream) {
    const float* x_gru = (const float*)d_in[0];  // (T, 96)
    const float* x_lin = (const float*)d_in[1];  // (T, 32)
    const float* h0    = (const float*)d_in[2];  // (128,)
    const float* w_ih  = (const float*)d_in[3];  // (384, 96)
    const float* w_hh  = (const float*)d_in[4];  // (384, 128)
    const float* b_ih  = (const float*)d_in[5];  // (384,)
    const float* b_n   = (const float*)d_in[6];  // (128,)
    const float* lbias = (const float*)d_in[7];  // (1,)
    float* out = (float*)d_out;                  // (T, 1)

    int T = in_sizes[0] / IN_SIZE;
    float* igates = (float*)d_ws;                    // T*384 floats = 96 MiB
    float* hlin   = (float*)d_ws + (size_t)T * H3;   // T*32 floats  =  8 MiB

    igates_kernel<<<T / 16, 384, 0, stream>>>(x_gru, w_ih, b_ih, igates, T);
    scan_kernel<<<1, 512, 0, stream>>>(igates, h0, w_hh, b_n, hlin, T);
    readout_kernel<<<(T * 8 + 255) / 256, 256, 0, stream>>>(hlin, x_lin, lbias, out, T);
}

// Round 9
// 32010.300 us; speedup vs baseline: 1.5231x; 1.0899x over previous
//
#include <hip/hip_runtime.h>
#include <math.h>

#define IN_SIZE 96
#define HID 128
#define H3 384
#define LIN_IN 32

// ---------------------------------------------------------------------------
// Kernel A (parallel): igates[t][j] = dot(input_GRU[t,:], w_ih[j,:]) + b_ih[j]
// ---------------------------------------------------------------------------
__global__ __launch_bounds__(384, 2)
void igates_kernel(const float* __restrict__ x, const float* __restrict__ w_ih,
                   const float* __restrict__ b_ih, float* __restrict__ ig, int T)
{
    const int TT = 16;
    int t0 = blockIdx.x * TT;
    int j = threadIdx.x; // 0..383
    __shared__ __align__(16) float xs[TT * IN_SIZE]; // 6 KB
    for (int idx = j; idx < TT * IN_SIZE; idx += H3)
        xs[idx] = x[(size_t)t0 * IN_SIZE + idx];
    __syncthreads();

    float acc[TT];
    float b = b_ih[j];
#pragma unroll
    for (int tt = 0; tt < TT; tt++) acc[tt] = b;

    const float4* w4 = (const float4*)(w_ih + (size_t)j * IN_SIZE);
#pragma unroll
    for (int k = 0; k < IN_SIZE / 4; k++) {
        float4 wv = w4[k];
#pragma unroll
        for (int tt = 0; tt < TT; tt++) {
            const float4* xv4 = (const float4*)(xs + tt * IN_SIZE);
            float4 xv = xv4[k];
            acc[tt] = fmaf(wv.x, xv.x, acc[tt]);
            acc[tt] = fmaf(wv.y, xv.y, acc[tt]);
            acc[tt] = fmaf(wv.z, xv.z, acc[tt]);
            acc[tt] = fmaf(wv.w, xv.w, acc[tt]);
        }
    }
#pragma unroll
    for (int tt = 0; tt < TT; tt++)
        ig[(size_t)(t0 + tt) * H3 + j] = acc[tt];
}

// ---------------------------------------------------------------------------
// Kernel B (sequential scan): one workgroup, 512 threads = 8 waves (2/SIMD).
// tid -> j = tid>>2 (hidden unit), kseg = tid&3 (32-wide k slice).
// Thread owns all three gate rows {j, j+128, j+256}; quad DPP k-combine puts
// hr,hz,hn in the kseg==0 lane which computes hnew[j]: one barrier/step.
//
// *** NUMERICS ARE FROZEN (R7/R8 lesson) ***
// The 65536-step recurrence is chaotic: any ulp change amplifies ~1e6x.
// R7/R8 used packed v_pk_fma_f32 (__builtin_elementwise_fma on float2) and
// BOTH failed at absmax 0.28125 even with a source-level reduction tree that
// should have been bit-identical -- the packed path does NOT reproduce the
// scalar-fma bits on this toolchain. The matvec below is VERBATIM the R6
// kernel that passed at absmax 0.0625: scalar fmaf, float4 accumulators,
// reduction (x+y)+(z+w), quad_sum via DPP. DO NOT TOUCH THE ARITHMETIC.
// Only scheduling changes are allowed:
//  - DEPTH-2 PREFETCH, NO ROTATION (bit-neutral: same values consumed):
//    step loop unrolled x2 with two register sets; each half consumes its
//    set then refills it for step+2, so the vmcnt wait lands ~2 steps
//    (~1700 cyc) after issue -> HBM-miss latency covered. (R6 rotated
//    registers at iteration end, forcing the wait within the same step.)
//  - Incremental prefetch pointer (no per-step 64-bit mul); refill guarded
//    by a uniform scalar branch (skipped only in the last 2 iterations).
// Weights literal-indexed (dynamic index spills to scratch -- R2).
// h layout padded (hs[kseg*36+off]): 0 bank conflicts (verified R4/R5).
// Raw "lgkmcnt(0); s_barrier" keeps global loads in flight (R4 lesson:
// __syncthreads drains vmcnt(0) and kills the prefetch).
// ---------------------------------------------------------------------------
__device__ __forceinline__ void fma4(float4& acc, const float4& wv, const float4& hv)
{
    acc.x = fmaf(wv.x, hv.x, acc.x);
    acc.y = fmaf(wv.y, hv.y, acc.y);
    acc.z = fmaf(wv.z, hv.z, acc.z);
    acc.w = fmaf(wv.w, hv.w, acc.w);
}

__device__ __forceinline__ float quad_sum(float x)
{
    float t;
    t = __int_as_float(__builtin_amdgcn_mov_dpp(__float_as_int(x), 0xB1, 0xF, 0xF, true)); // [1,0,3,2]
    x += t;
    t = __int_as_float(__builtin_amdgcn_mov_dpp(__float_as_int(x), 0x4E, 0xF, 0xF, true)); // [2,3,0,1]
    x += t;
    return x;
}

__device__ __forceinline__ void fast_barrier()
{
    asm volatile("s_waitcnt lgkmcnt(0)\n\ts_barrier" ::: "memory");
}

#define HPAD 36  // 32 floats per k-segment + 4 pad

__global__ __launch_bounds__(512, 2)
void scan_kernel(const float* __restrict__ ig, const float* __restrict__ h0,
                 const float* __restrict__ w_hh, const float* __restrict__ b_n,
                 float* __restrict__ hlin, int T)
{
    __shared__ __align__(16) float hs[4 * HPAD];

    const int tid = threadIdx.x;     // 0..511
    const int j = tid >> 2;          // 0..127
    const int kseg = tid & 3;        // 0..3
    const bool gate_lane = (kseg == 0);

    // weights for rows j, j+128, j+256 (k slice kseg*32..+32) -> registers
    float4 w0[8], w1[8], w2[8];
    {
        const float* b0 = w_hh + (size_t)j * HID + kseg * 32;
        const float* b1 = w_hh + (size_t)(j + HID) * HID + kseg * 32;
        const float* b2 = w_hh + (size_t)(j + 2 * HID) * HID + kseg * 32;
#pragma unroll
        for (int k = 0; k < 8; k++) {
            w0[k] = ((const float4*)b0)[k];
            w1[k] = ((const float4*)b1)[k];
            w2[k] = ((const float4*)b2)[k];
        }
    }
    if (tid < HID) hs[(tid >> 5) * HPAD + (tid & 31)] = h0[tid];

    // two gate-input register sets: P0 = even step, P1 = odd step
    float bn = 0.f;
    float p00 = 0.f, p01 = 0.f, p02 = 0.f;  // set 0
    float p10 = 0.f, p11 = 0.f, p12 = 0.f;  // set 1
    if (gate_lane) {
        bn = b_n[j];
        p00 = ig[j];
        p01 = ig[HID + j];
        p02 = ig[2 * HID + j];
        const float* q = ig + H3;
        p10 = q[j];
        p11 = q[HID + j];
        p12 = q[2 * HID + j];
    }
    __syncthreads();

    const float4* hp = (const float4*)(hs + kseg * HPAD);
    const int hwidx = (j >> 5) * HPAD + (j & 31);

    // incrementally-advanced prefetch base: points at ig[(s+2)*H3 + j]
    const float* pf = ig + (size_t)2 * H3 + j;
    float* hl = hlin + j;  // hlin[step*LIN_IN + j], advanced by LIN_IN

#define MATVEC_GATES(C0, C1, C2, DO_PREFETCH)                                  \
    {                                                                          \
        float4 a0 = {0.f, 0.f, 0.f, 0.f}, a1 = a0, a2 = a0;                    \
        _Pragma("unroll")                                                      \
        for (int kk = 0; kk < 8; kk++) {                                       \
            float4 hv = hp[kk];                                                \
            fma4(a0, w0[kk], hv);                                              \
            fma4(a1, w1[kk], hv);                                              \
            fma4(a2, w2[kk], hv);                                              \
        }                                                                      \
        float s0 = (a0.x + a0.y) + (a0.z + a0.w);                              \
        float s1 = (a1.x + a1.y) + (a1.z + a1.w);                              \
        float s2 = (a2.x + a2.y) + (a2.z + a2.w);                              \
        s0 = quad_sum(s0); s1 = quad_sum(s1); s2 = quad_sum(s2);               \
        if (gate_lane) {                                                       \
            float hprev = hs[hwidx];                                           \
            float er = __expf(-(C0 + s0));                                     \
            float r = __builtin_amdgcn_rcpf(1.f + er);                         \
            float ez = __expf(-(C1 + s1));                                     \
            float z = __builtin_amdgcn_rcpf(1.f + ez);                         \
            float xn = C2 + r * (s2 + bn);                                     \
            float e2 = __expf(-2.f * fabsf(xn));                               \
            float th = (1.f - e2) * __builtin_amdgcn_rcpf(1.f + e2);           \
            float nn = copysignf(th, xn);                                      \
            float hnew = nn + z * (hprev - nn);                                \
            hs[hwidx] = hnew;                                                  \
            if (j < LIN_IN) *hl = hnew;                                        \
            if (DO_PREFETCH) {  /* refill this set for step+2 */               \
                C0 = pf[0];                                                    \
                C1 = pf[HID];                                                  \
                C2 = pf[2 * HID];                                              \
            }                                                                  \
        }                                                                      \
        hl += LIN_IN;                                                          \
        pf += H3;                                                              \
        fast_barrier();                                                        \
    }

    int s = 0;
    for (; s + 4 <= T; s += 2) {           // both halves may prefetch
        MATVEC_GATES(p00, p01, p02, true)
        MATVEC_GATES(p10, p11, p12, true)
    }
    // tail: last two steps, no prefetch (uniform, outside the hot loop)
    MATVEC_GATES(p00, p01, p02, false)
    MATVEC_GATES(p10, p11, p12, false)
#undef MATVEC_GATES
}

// ---------------------------------------------------------------------------
// Kernel C (parallel): out[t] = dot(hlin[t,:], xlin[t,:]) + lbias
// ---------------------------------------------------------------------------
__global__ __launch_bounds__(256)
void readout_kernel(const float* __restrict__ hlin, const float* __restrict__ xlin,
                    const float* __restrict__ lbias, float* __restrict__ out, int T)
{
    int gid = blockIdx.x * 256 + threadIdx.x;
    int t = gid >> 3;
    int seg = gid & 7;
    if (t < T) {
        float4 hv = ((const float4*)hlin)[(size_t)t * 8 + seg];
        float4 xv = ((const float4*)xlin)[(size_t)t * 8 + seg];
        float p = hv.x * xv.x + hv.y * xv.y + hv.z * xv.z + hv.w * xv.w;
        p += __shfl_xor(p, 1);
        p += __shfl_xor(p, 2);
        p += __shfl_xor(p, 4);
        if (seg == 0) out[t] = p + lbias[0];
    }
}

extern "C" void kernel_launch(void* const* d_in, const int* in_sizes, int n_in,
                              void* d_out, int out_size, void* d_ws, size_t ws_size,
                              hipStream_t stream) {
    const float* x_gru = (const float*)d_in[0];  // (T, 96)
    const float* x_lin = (const float*)d_in[1];  // (T, 32)
    const float* h0    = (const float*)d_in[2];  // (128,)
    const float* w_ih  = (const float*)d_in[3];  // (384, 96)
    const float* w_hh  = (const float*)d_in[4];  // (384, 128)
    const float* b_ih  = (const float*)d_in[5];  // (384,)
    const float* b_n   = (const float*)d_in[6];  // (128,)
    const float* lbias = (const float*)d_in[7];  // (1,)
    float* out = (float*)d_out;                  // (T, 1)

    int T = in_sizes[0] / IN_SIZE;               // 65536 (even)
    float* igates = (float*)d_ws;                    // T*384 floats = 96 MiB
    float* hlin   = (float*)d_ws + (size_t)T * H3;   // T*32 floats  =  8 MiB

    igates_kernel<<<T / 16, 384, 0, stream>>>(x_gru, w_ih, b_ih, igates, T);
    scan_kernel<<<1, 512, 0, stream>>>(igates, h0, w_hh, b_n, hlin, T);
    readout_kernel<<<(T * 8 + 255) / 256, 256, 0, stream>>>(hlin, x_lin, lbias, out, T);
}

// Round 10
// 31916.373 us; speedup vs baseline: 1.5276x; 1.0029x over previous
//
#include <hip/hip_runtime.h>
#include <math.h>

#define IN_SIZE 96
#define HID 128
#define H3 384
#define LIN_IN 32

// ---------------------------------------------------------------------------
// Kernel A (parallel): igates[t][j] = dot(input_GRU[t,:], w_ih[j,:]) + b_ih[j]
// ---------------------------------------------------------------------------
__global__ __launch_bounds__(384, 2)
void igates_kernel(const float* __restrict__ x, const float* __restrict__ w_ih,
                   const float* __restrict__ b_ih, float* __restrict__ ig, int T)
{
    const int TT = 16;
    int t0 = blockIdx.x * TT;
    int j = threadIdx.x; // 0..383
    __shared__ __align__(16) float xs[TT * IN_SIZE]; // 6 KB
    for (int idx = j; idx < TT * IN_SIZE; idx += H3)
        xs[idx] = x[(size_t)t0 * IN_SIZE + idx];
    __syncthreads();

    float acc[TT];
    float b = b_ih[j];
#pragma unroll
    for (int tt = 0; tt < TT; tt++) acc[tt] = b;

    const float4* w4 = (const float4*)(w_ih + (size_t)j * IN_SIZE);
#pragma unroll
    for (int k = 0; k < IN_SIZE / 4; k++) {
        float4 wv = w4[k];
#pragma unroll
        for (int tt = 0; tt < TT; tt++) {
            const float4* xv4 = (const float4*)(xs + tt * IN_SIZE);
            float4 xv = xv4[k];
            acc[tt] = fmaf(wv.x, xv.x, acc[tt]);
            acc[tt] = fmaf(wv.y, xv.y, acc[tt]);
            acc[tt] = fmaf(wv.z, xv.z, acc[tt]);
            acc[tt] = fmaf(wv.w, xv.w, acc[tt]);
        }
    }
#pragma unroll
    for (int tt = 0; tt < TT; tt++)
        ig[(size_t)(t0 + tt) * H3 + j] = acc[tt];
}

// ---------------------------------------------------------------------------
// Kernel B (sequential scan): one workgroup, 512 threads = 8 waves (2/SIMD).
// tid -> j = tid>>2 (hidden unit), kseg = tid&3 (32-wide k slice).
// Thread owns all three gate rows {j, j+128, j+256}; quad DPP k-combine puts
// hr,hz,hn in the kseg==0 lane which computes hnew[j]: one barrier/step.
//
// *** NUMERICS ARE FROZEN (R7/R8 lesson) ***
// 65536-step recurrence is chaotic; packed v_pk_fma_f32 failed twice at
// absmax 0.28125. Matvec is VERBATIM the form that passes at 0.0625:
// scalar fmaf, float4 accumulators, (x+y)+(z+w), quad_sum DPP. DO NOT
// TOUCH THE ARITHMETIC.
//
// R9 change (vs R8's 1170 cyc/step, issue-port saturated):
//  - amdgpu_waves_per_eu(2,2): R8's VGPR_Count=68 with 96 weight floats
//    per thread means the compiler spilled weights to AGPRs (its
//    occupancy heuristic targets the 64-reg class; AGPR spills are "free"
//    in its model) and issued ~96 v_accvgpr_read per thread per step
//    (~384 cyc/SIMD/step -- the gap between the 610-cyc census and the
//    1130 measured busy cycles). Declaring max 2 waves/EU legalizes the
//    256-reg class so weights live in arch VGPRs. flat_work_group_size
//    pins the block shape.
// Scheduling levers retained from R8 (all bit-neutral):
//  - depth-2 prefetch, two register sets, no rotation; incremental pf ptr
//  - raw "lgkmcnt(0); s_barrier" (keeps global loads in flight)
//  - padded h layout (0 bank conflicts, verified)
// ---------------------------------------------------------------------------
__device__ __forceinline__ void fma4(float4& acc, const float4& wv, const float4& hv)
{
    acc.x = fmaf(wv.x, hv.x, acc.x);
    acc.y = fmaf(wv.y, hv.y, acc.y);
    acc.z = fmaf(wv.z, hv.z, acc.z);
    acc.w = fmaf(wv.w, hv.w, acc.w);
}

__device__ __forceinline__ float quad_sum(float x)
{
    float t;
    t = __int_as_float(__builtin_amdgcn_mov_dpp(__float_as_int(x), 0xB1, 0xF, 0xF, true)); // [1,0,3,2]
    x += t;
    t = __int_as_float(__builtin_amdgcn_mov_dpp(__float_as_int(x), 0x4E, 0xF, 0xF, true)); // [2,3,0,1]
    x += t;
    return x;
}

__device__ __forceinline__ void fast_barrier()
{
    asm volatile("s_waitcnt lgkmcnt(0)\n\ts_barrier" ::: "memory");
}

#define HPAD 36  // 32 floats per k-segment + 4 pad

__global__
__attribute__((amdgpu_flat_work_group_size(512, 512), amdgpu_waves_per_eu(2, 2)))
void scan_kernel(const float* __restrict__ ig, const float* __restrict__ h0,
                 const float* __restrict__ w_hh, const float* __restrict__ b_n,
                 float* __restrict__ hlin, int T)
{
    __shared__ __align__(16) float hs[4 * HPAD];

    const int tid = threadIdx.x;     // 0..511
    const int j = tid >> 2;          // 0..127
    const int kseg = tid & 3;        // 0..3
    const bool gate_lane = (kseg == 0);

    // weights for rows j, j+128, j+256 (k slice kseg*32..+32) -> registers
    float4 w0[8], w1[8], w2[8];
    {
        const float* b0 = w_hh + (size_t)j * HID + kseg * 32;
        const float* b1 = w_hh + (size_t)(j + HID) * HID + kseg * 32;
        const float* b2 = w_hh + (size_t)(j + 2 * HID) * HID + kseg * 32;
#pragma unroll
        for (int k = 0; k < 8; k++) {
            w0[k] = ((const float4*)b0)[k];
            w1[k] = ((const float4*)b1)[k];
            w2[k] = ((const float4*)b2)[k];
        }
    }
    if (tid < HID) hs[(tid >> 5) * HPAD + (tid & 31)] = h0[tid];

    // two gate-input register sets: P0 = even step, P1 = odd step
    float bn = 0.f;
    float p00 = 0.f, p01 = 0.f, p02 = 0.f;  // set 0
    float p10 = 0.f, p11 = 0.f, p12 = 0.f;  // set 1
    if (gate_lane) {
        bn = b_n[j];
        p00 = ig[j];
        p01 = ig[HID + j];
        p02 = ig[2 * HID + j];
        const float* q = ig + H3;
        p10 = q[j];
        p11 = q[HID + j];
        p12 = q[2 * HID + j];
    }
    __syncthreads();

    const float4* hp = (const float4*)(hs + kseg * HPAD);
    const int hwidx = (j >> 5) * HPAD + (j & 31);

    // incrementally-advanced prefetch base: points at ig[(s+2)*H3 + j]
    const float* pf = ig + (size_t)2 * H3 + j;
    float* hl = hlin + j;  // hlin[step*LIN_IN + j], advanced by LIN_IN

#define MATVEC_GATES(C0, C1, C2, DO_PREFETCH)                                  \
    {                                                                          \
        float4 a0 = {0.f, 0.f, 0.f, 0.f}, a1 = a0, a2 = a0;                    \
        _Pragma("unroll")                                                      \
        for (int kk = 0; kk < 8; kk++) {                                       \
            float4 hv = hp[kk];                                                \
            fma4(a0, w0[kk], hv);                                              \
            fma4(a1, w1[kk], hv);                                              \
            fma4(a2, w2[kk], hv);                                              \
        }                                                                      \
        float s0 = (a0.x + a0.y) + (a0.z + a0.w);                              \
        float s1 = (a1.x + a1.y) + (a1.z + a1.w);                              \
        float s2 = (a2.x + a2.y) + (a2.z + a2.w);                              \
        s0 = quad_sum(s0); s1 = quad_sum(s1); s2 = quad_sum(s2);               \
        if (gate_lane) {                                                       \
            float hprev = hs[hwidx];                                           \
            float er = __expf(-(C0 + s0));                                     \
            float r = __builtin_amdgcn_rcpf(1.f + er);                         \
            float ez = __expf(-(C1 + s1));                                     \
            float z = __builtin_amdgcn_rcpf(1.f + ez);                         \
            float xn = C2 + r * (s2 + bn);                                     \
            float e2 = __expf(-2.f * fabsf(xn));                               \
            float th = (1.f - e2) * __builtin_amdgcn_rcpf(1.f + e2);           \
            float nn = copysignf(th, xn);                                      \
            float hnew = nn + z * (hprev - nn);                                \
            hs[hwidx] = hnew;                                                  \
            if (j < LIN_IN) *hl = hnew;                                        \
            if (DO_PREFETCH) {  /* refill this set for step+2 */               \
                C0 = pf[0];                                                    \
                C1 = pf[HID];                                                  \
                C2 = pf[2 * HID];                                              \
            }                                                                  \
        }                                                                      \
        hl += LIN_IN;                                                          \
        pf += H3;                                                              \
        fast_barrier();                                                        \
    }

    int s = 0;
    for (; s + 4 <= T; s += 2) {           // both halves may prefetch
        MATVEC_GATES(p00, p01, p02, true)
        MATVEC_GATES(p10, p11, p12, true)
    }
    // tail: last two steps, no prefetch (uniform, outside the hot loop)
    MATVEC_GATES(p00, p01, p02, false)
    MATVEC_GATES(p10, p11, p12, false)
#undef MATVEC_GATES
}

// ---------------------------------------------------------------------------
// Kernel C (parallel): out[t] = dot(hlin[t,:], xlin[t,:]) + lbias
// ---------------------------------------------------------------------------
__global__ __launch_bounds__(256)
void readout_kernel(const float* __restrict__ hlin, const float* __restrict__ xlin,
                    const float* __restrict__ lbias, float* __restrict__ out, int T)
{
    int gid = blockIdx.x * 256 + threadIdx.x;
    int t = gid >> 3;
    int seg = gid & 7;
    if (t < T) {
        float4 hv = ((const float4*)hlin)[(size_t)t * 8 + seg];
        float4 xv = ((const float4*)xlin)[(size_t)t * 8 + seg];
        float p = hv.x * xv.x + hv.y * xv.y + hv.z * xv.z + hv.w * xv.w;
        p += __shfl_xor(p, 1);
        p += __shfl_xor(p, 2);
        p += __shfl_xor(p, 4);
        if (seg == 0) out[t] = p + lbias[0];
    }
}

extern "C" void kernel_launch(void* const* d_in, const int* in_sizes, int n_in,
                              void* d_out, int out_size, void* d_ws, size_t ws_size,
                              hipStream_t stream) {
    const float* x_gru = (const float*)d_in[0];  // (T, 96)
    const float* x_lin = (const float*)d_in[1];  // (T, 32)
    const float* h0    = (const float*)d_in[2];  // (128,)
    const float* w_ih  = (const float*)d_in[3];  // (384, 96)
    const float* w_hh  = (const float*)d_in[4];  // (384, 128)
    const float* b_ih  = (const float*)d_in[5];  // (384,)
    const float* b_n   = (const float*)d_in[6];  // (128,)
    const float* lbias = (const float*)d_in[7];  // (1,)
    float* out = (float*)d_out;                  // (T, 1)

    int T = in_sizes[0] / IN_SIZE;               // 65536 (even)
    float* igates = (float*)d_ws;                    // T*384 floats = 96 MiB
    float* hlin   = (float*)d_ws + (size_t)T * H3;   // T*32 floats  =  8 MiB

    igates_kernel<<<T / 16, 384, 0, stream>>>(x_gru, w_ih, b_ih, igates, T);
    scan_kernel<<<1, 512, 0, stream>>>(igates, h0, w_hh, b_n, hlin, T);
    readout_kernel<<<(T * 8 + 255) / 256, 256, 0, stream>>>(hlin, x_lin, lbias, out, T);
}